// Round 6
// baseline (527.499 us; speedup 1.0000x reference)
//
#include <hip/hip_runtime.h>
#include <stdint.h>

typedef unsigned short u16;
typedef unsigned int u32;
typedef __attribute__((ext_vector_type(4))) float f32x4;
typedef __attribute__((ext_vector_type(16))) float f32x16;
typedef __attribute__((ext_vector_type(8))) short s16x8;
typedef __attribute__((ext_vector_type(4))) short s16x4;
typedef __attribute__((ext_vector_type(2))) unsigned int u32x2;
typedef __attribute__((ext_vector_type(4))) unsigned int u32x4;
typedef __attribute__((ext_vector_type(8))) int i32x8;

__device__ __forceinline__ u16 f2bf(float x){
  unsigned u = __builtin_bit_cast(unsigned, x);
  u += 0x7fffu + ((u >> 16) & 1u);
  return (u16)(u >> 16);
}
__device__ __forceinline__ float bf2f(u16 b){
  return __builtin_bit_cast(float, (unsigned)b << 16);
}
__device__ __forceinline__ u32 pk_fp8x4(float a, float b, float c, float d){
  int w = 0;
  w = __builtin_amdgcn_cvt_pk_fp8_f32(a, b, w, false);
  w = __builtin_amdgcn_cvt_pk_fp8_f32(c, d, w, true);
  return (u32)w;
}

// ---------------- device helpers ----------------

__device__ __forceinline__ void tcvtT_dev(const float* __restrict__ src, u16* __restrict__ dst,
                                          int K, int N, int bx, int by, char* smem){
  float (*t)[33] = (float (*)[33])smem;
  int tx = threadIdx.x & 31, ty = threadIdx.x >> 5;
  int n0 = bx * 32, k0 = by * 32;
  #pragma unroll
  for (int i = 0; i < 4; i++)
    t[ty + 8 * i][tx] = src[(size_t)(k0 + ty + 8 * i) * N + n0 + tx];
  __syncthreads();
  #pragma unroll
  for (int i = 0; i < 4; i++)
    dst[(size_t)(n0 + ty + 8 * i) * K + k0 + tx] = f2bf(t[tx][ty + 8 * i]);
}

__device__ __forceinline__ void bn_dev(const float* __restrict__ g, const float* __restrict__ b,
                                       const float* __restrict__ m, const float* __restrict__ v,
                                       const float* __restrict__ lin_b,
                                       float* __restrict__ s, float* __restrict__ bb,
                                       int n, int blk){
  int i = blk * 256 + threadIdx.x;
  if (i < n){
    float sc = g[i] * rsqrtf(v[i] + 1e-5f);
    s[i] = sc;
    bb[i] = (lin_b[i] - m[i]) * sc + b[i];
  }
}

// ---------------- prep0: w1 transpose-convert + bn1 ----------------
__global__ __launch_bounds__(256) void prep0_kernel(
    const float* __restrict__ enc_w1, u16* __restrict__ w1t,
    const float* __restrict__ g, const float* __restrict__ b,
    const float* __restrict__ m, const float* __restrict__ v,
    const float* __restrict__ lin_b, float* __restrict__ s1, float* __restrict__ bb1)
{
  __shared__ char smem[32 * 33 * 4 + 64];
  if (blockIdx.x < 512)
    tcvtT_dev(enc_w1, w1t, 1024, 512, blockIdx.x & 15, blockIdx.x >> 4, smem);
  else
    bn_dev(g, b, m, v, lin_b, s1, bb1, 512, blockIdx.x - 512);
}

// ---------------- fused enc1 GEMM + degree/fp8-convert + small preps ----------------
__global__ __launch_bounds__(256) void enc1_deg_kernel(
    const float* __restrict__ feature, const u16* __restrict__ w1t,
    u16* __restrict__ h1, const float* __restrict__ cs, const float* __restrict__ cb,
    const float* __restrict__ adj, unsigned char* __restrict__ adj8,
    float* __restrict__ dis,
    const float* __restrict__ enc_w2, u16* __restrict__ w2t,
    const float* __restrict__ gcn1_w, u16* __restrict__ g1t,
    const float* __restrict__ gcn2_w, u16* __restrict__ g2t,
    const float* __restrict__ bn2_g, const float* __restrict__ bn2_b,
    const float* __restrict__ bn2_m, const float* __restrict__ bn2_v,
    const float* __restrict__ enc_b2, float* __restrict__ s2, float* __restrict__ bb2)
{
  constexpr int BM = 128, BN = 256, BK = 64, WM = 2, WN = 2;
  constexpr int N = 512, K = 1024, NADJ = 16384;
  constexpr int WTM = BM / WM, WTN = BN / WN, FM = WTM / 16, FN = WTN / 16;
  constexpr int AIT = (BM * BK) / (256 * 4);
  constexpr int BIT = (BN * BK) / (256 * 8);

  __shared__ __align__(16) char smem[BM * BK * 2 + BN * BK * 2];

  if (blockIdx.x >= 16640){
    int p = blockIdx.x - 16640;
    if (p < 128)       tcvtT_dev(enc_w2, w2t, 512, 256, p & 7, p >> 3, smem);
    else if (p < 192){ int l = p - 128; tcvtT_dev(gcn1_w, g1t, 256, 256, l & 7, l >> 3, smem); }
    else if (p < 224){ int l = p - 192; tcvtT_dev(gcn2_w, g2t, 256, 128, l & 3, l >> 2, smem); }
    else               bn_dev(bn2_g, bn2_b, bn2_m, bn2_v, enc_b2, s2, bb2, 256, 0);
    return;
  }

  if (blockIdx.x >= 256){
    int row = blockIdx.x - 256;
    const float* rp = adj + (size_t)row * NADJ;
    unsigned char* wp = adj8 + (size_t)row * NADJ;
    float s = 0.f;
    #pragma unroll
    for (int it = 0; it < 4; ++it){
      const float* p = rp + it * 4096 + threadIdx.x * 16;
      f32x4 v[4];
      #pragma unroll
      for (int j = 0; j < 4; ++j) v[j] = *(const f32x4*)(p + 4 * j);
      u32x4 o;
      #pragma unroll
      for (int j = 0; j < 4; ++j){
        s += (v[j][0] + v[j][1]) + (v[j][2] + v[j][3]);
        o[j] = pk_fp8x4(v[j][0], v[j][1], v[j][2], v[j][3]);
      }
      *(u32x4*)(wp + it * 4096 + threadIdx.x * 16) = o;
    }
    #pragma unroll
    for (int d = 32; d > 0; d >>= 1) s += __shfl_down(s, d, 64);
    float* ps = (float*)smem;
    if ((threadIdx.x & 63) == 0) ps[threadIdx.x >> 6] = s;
    __syncthreads();
    if (threadIdx.x == 0) dis[row] = rsqrtf((ps[0] + ps[1]) + (ps[2] + ps[3]));
    return;
  }

  // ---- enc1 GEMM tile ----
  u16* As = (u16*)smem;
  u16* Bs = (u16*)(smem + BM * BK * 2);
  const int tid = threadIdx.x;
  const int lane = tid & 63;
  const int wid = tid >> 6;
  const int wr = wid / WN;
  const int wc = wid % WN;
  const int bm = (blockIdx.x & 127) * BM;
  const int bn = (blockIdx.x >> 7) * BN;

  f32x4 arf[AIT];
  s16x8 brb[BIT];

  auto load_tiles = [&](int k0){
    #pragma unroll
    for (int i = 0; i < AIT; i++){
      int e = (i * 256 + tid) * 4; int r = e / BK, c = e % BK;
      arf[i] = *(const f32x4*)(feature + (size_t)(bm + r) * K + k0 + c);
    }
    #pragma unroll
    for (int i = 0; i < BIT; i++){
      int e = (i * 256 + tid) * 8; int r = e / BK, c = e % BK;
      brb[i] = *(const s16x8*)(w1t + (size_t)(bn + r) * K + k0 + c);
    }
  };
  auto store_tiles = [&](){
    char* Ac = (char*)As; char* Bc = (char*)Bs;
    #pragma unroll
    for (int i = 0; i < AIT; i++){
      int e = (i * 256 + tid) * 4; int r = e / BK, c = e % BK;
      int off = ((r * BK + c) * 2) ^ ((r & 7) << 4);
      s16x4 o;
      o[0] = (short)f2bf(arf[i][0]); o[1] = (short)f2bf(arf[i][1]);
      o[2] = (short)f2bf(arf[i][2]); o[3] = (short)f2bf(arf[i][3]);
      *(s16x4*)(Ac + off) = o;
    }
    #pragma unroll
    for (int i = 0; i < BIT; i++){
      int e = (i * 256 + tid) * 8; int r = e / BK, c = e % BK;
      int off = ((r * BK + c) * 2) ^ ((r & 7) << 4);
      *(s16x8*)(Bc + off) = brb[i];
    }
  };

  f32x4 acc[FM][FN];
  #pragma unroll
  for (int m = 0; m < FM; m++)
    #pragma unroll
    for (int n = 0; n < FN; n++)
      acc[m][n] = (f32x4){0.f, 0.f, 0.f, 0.f};

  const int arow0 = wr * WTM + (lane & 15);
  const int brow0 = wc * WTN + (lane & 15);
  const int kof = (lane >> 4) * 8;

  load_tiles(0);
  for (int kt = 0; kt < K / BK; ++kt){
    __syncthreads();
    store_tiles();
    __syncthreads();
    if (kt + 1 < K / BK) load_tiles((kt + 1) * BK);
    const char* Ac = (const char*)As;
    const char* Bc = (const char*)Bs;
    #pragma unroll
    for (int ks = 0; ks < BK / 32; ++ks){
      s16x8 af[FM], bfr[FN];
      #pragma unroll
      for (int m = 0; m < FM; m++){
        int r = arow0 + m * 16;
        af[m] = *(const s16x8*)(Ac + (((r * BK + ks * 32 + kof) * 2) ^ ((r & 7) << 4)));
      }
      #pragma unroll
      for (int n = 0; n < FN; n++){
        int r = brow0 + n * 16;
        bfr[n] = *(const s16x8*)(Bc + (((r * BK + ks * 32 + kof) * 2) ^ ((r & 7) << 4)));
      }
      #pragma unroll
      for (int m = 0; m < FM; m++)
        #pragma unroll
        for (int n = 0; n < FN; n++)
          acc[m][n] = __builtin_amdgcn_mfma_f32_16x16x32_bf16(af[m], bfr[n], acc[m][n], 0, 0, 0);
    }
  }
  #pragma unroll
  for (int m = 0; m < FM; m++){
    #pragma unroll
    for (int n = 0; n < FN; n++){
      int col = bn + wc * WTN + n * 16 + (lane & 15);
      int row0 = bm + wr * WTM + m * 16 + (lane >> 4) * 4;
      #pragma unroll
      for (int r4 = 0; r4 < 4; r4++){
        float vv = fmaxf(acc[m][n][r4] * cs[col] + cb[col], 0.f);
        h1[(size_t)(row0 + r4) * N + col] = f2bf(vv);
      }
    }
  }
}

// ---------------- fused enc2 + gcn1-prescale (512 thr): tT = fp8(SC*dis*(relu(bn2(h1@w2))@g1w))^T --
__global__ __launch_bounds__(512, 2)
void h2tT_kernel(const u16* __restrict__ h1, const u16* __restrict__ w2t,
                 const float* __restrict__ s2, const float* __restrict__ bb2,
                 const u16* __restrict__ g1t, const float* __restrict__ dis,
                 unsigned char* __restrict__ tT)
{
  constexpr int M = 16384, K1 = 512, K2 = 256, BK = 64;
  constexpr float SC = 256.f;

  __shared__ u16 As[64 * BK];     // 8 KB
  __shared__ u16 Bs[256 * BK];    // 32 KB
  __shared__ u16 H2s[64 * 256];   // 32 KB

  const int tid = threadIdx.x;
  const int lane = tid & 63;
  const int wid = tid >> 6;       // 8 waves: wr=wid>>2 (M), wc=wid&3 (N)
  const int wr = wid >> 2;
  const int wc = wid & 3;
  const int bm = blockIdx.x * 64;
  const int kof = (lane >> 4) * 8;

  // ---- phase 1: H2s = relu(bn2(h1[bm:bm+64][:] @ w2)) ----
  {
    s16x8 arb, brb[4];
    auto load1 = [&](int k0){
      { int e = tid * 8; int r = e >> 6, c = e & 63;
        arb = *(const s16x8*)(h1 + (size_t)(bm + r) * K1 + k0 + c); }
      #pragma unroll
      for (int i = 0; i < 4; i++){
        int e = (i * 512 + tid) * 8; int r = e >> 6, c = e & 63;
        brb[i] = *(const s16x8*)(w2t + (size_t)r * K1 + k0 + c);
      }
    };
    auto store1 = [&](){
      char* Ac = (char*)As; char* Bc = (char*)Bs;
      { int e = tid * 8; int r = e >> 6, c = e & 63;
        *(s16x8*)(Ac + (((r * BK + c) * 2) ^ ((r & 7) << 4))) = arb; }
      #pragma unroll
      for (int i = 0; i < 4; i++){
        int e = (i * 512 + tid) * 8; int r = e >> 6, c = e & 63;
        *(s16x8*)(Bc + (((r * BK + c) * 2) ^ ((r & 7) << 4))) = brb[i];
      }
    };

    f32x4 acc[2][4];
    #pragma unroll
    for (int m = 0; m < 2; m++)
      #pragma unroll
      for (int n = 0; n < 4; n++)
        acc[m][n] = (f32x4){0.f, 0.f, 0.f, 0.f};

    load1(0);
    for (int kt = 0; kt < K1 / BK; ++kt){
      __syncthreads();
      store1();
      __syncthreads();
      if (kt + 1 < K1 / BK) load1((kt + 1) * BK);
      const char* Ac = (const char*)As;
      const char* Bc = (const char*)Bs;
      #pragma unroll
      for (int ks = 0; ks < 2; ++ks){
        s16x8 af[2], bfr[4];
        #pragma unroll
        for (int m = 0; m < 2; m++){
          int r = wr * 32 + m * 16 + (lane & 15);
          af[m] = *(const s16x8*)(Ac + (((r * BK + ks * 32 + kof) * 2) ^ ((r & 7) << 4)));
        }
        #pragma unroll
        for (int n = 0; n < 4; n++){
          int r = wc * 64 + n * 16 + (lane & 15);
          bfr[n] = *(const s16x8*)(Bc + (((r * BK + ks * 32 + kof) * 2) ^ ((r & 7) << 4)));
        }
        #pragma unroll
        for (int m = 0; m < 2; m++)
          #pragma unroll
          for (int n = 0; n < 4; n++)
            acc[m][n] = __builtin_amdgcn_mfma_f32_16x16x32_bf16(af[m], bfr[n], acc[m][n], 0, 0, 0);
      }
    }
    __syncthreads();
    char* Hc = (char*)H2s;
    #pragma unroll
    for (int m = 0; m < 2; m++){
      #pragma unroll
      for (int n = 0; n < 4; n++){
        int col = wc * 64 + n * 16 + (lane & 15);
        int row0 = wr * 32 + m * 16 + (lane >> 4) * 4;
        #pragma unroll
        for (int r4 = 0; r4 < 4; r4++){
          int row = row0 + r4;
          float vv = fmaxf(acc[m][n][r4] * s2[col] + bb2[col], 0.f);
          *(u16*)(Hc + (((row * 256 + col) * 2) ^ ((row & 7) << 4))) = f2bf(vv);
        }
      }
    }
  }

  // ---- phase 2: tT = fp8(SC * dis * (H2s @ g1w))^T ----
  {
    s16x8 brb[4];
    auto load2 = [&](int k0){
      #pragma unroll
      for (int i = 0; i < 4; i++){
        int e = (i * 512 + tid) * 8; int r = e >> 6, c = e & 63;
        brb[i] = *(const s16x8*)(g1t + (size_t)r * K2 + k0 + c);
      }
    };
    auto store2 = [&](){
      char* Bc = (char*)Bs;
      #pragma unroll
      for (int i = 0; i < 4; i++){
        int e = (i * 512 + tid) * 8; int r = e >> 6, c = e & 63;
        *(s16x8*)(Bc + (((r * BK + c) * 2) ^ ((r & 7) << 4))) = brb[i];
      }
    };

    f32x4 acc[2][4];
    #pragma unroll
    for (int m = 0; m < 2; m++)
      #pragma unroll
      for (int n = 0; n < 4; n++)
        acc[m][n] = (f32x4){0.f, 0.f, 0.f, 0.f};

    load2(0);
    for (int kt = 0; kt < K2 / BK; ++kt){
      __syncthreads();
      store2();
      __syncthreads();
      if (kt + 1 < K2 / BK) load2((kt + 1) * BK);
      const char* Hc = (const char*)H2s;
      const char* Bc = (const char*)Bs;
      #pragma unroll
      for (int ks = 0; ks < 2; ++ks){
        s16x8 af[2], bfr[4];
        #pragma unroll
        for (int m = 0; m < 2; m++){
          int r = wr * 32 + m * 16 + (lane & 15);
          af[m] = *(const s16x8*)(Hc + (((r * 256 + kt * 64 + ks * 32 + kof) * 2) ^ ((r & 7) << 4)));
        }
        #pragma unroll
        for (int n = 0; n < 4; n++){
          int r = wc * 64 + n * 16 + (lane & 15);
          bfr[n] = *(const s16x8*)(Bc + (((r * BK + ks * 32 + kof) * 2) ^ ((r & 7) << 4)));
        }
        #pragma unroll
        for (int m = 0; m < 2; m++)
          #pragma unroll
          for (int n = 0; n < 4; n++)
            acc[m][n] = __builtin_amdgcn_mfma_f32_16x16x32_bf16(af[m], bfr[n], acc[m][n], 0, 0, 0);
      }
    }
    #pragma unroll
    for (int m = 0; m < 2; m++){
      #pragma unroll
      for (int n = 0; n < 4; n++){
        int col = wc * 64 + n * 16 + (lane & 15);
        int row0 = bm + wr * 32 + m * 16 + (lane >> 4) * 4;
        float v0 = acc[m][n][0] * dis[row0 + 0] * SC;
        float v1 = acc[m][n][1] * dis[row0 + 1] * SC;
        float v2 = acc[m][n][2] * dis[row0 + 2] * SC;
        float v3 = acc[m][n][3] * dis[row0 + 3] * SC;
        *(u32*)(tT + (size_t)col * M + row0) = pk_fp8x4(v0, v1, v2, v3);
      }
    }
  }
}

// ---------------- mx1 + t2 fused: adj8 @ tT -> h3(reg) -> LDS -> @ g2w -> t2T ----------------
__global__ __launch_bounds__(512, 4)
void mx1t2_kernel(const unsigned char* __restrict__ A8, const unsigned char* __restrict__ B8,
                  const float* __restrict__ dis, const float* __restrict__ g1b,
                  const u16* __restrict__ g2t, unsigned char* __restrict__ t2T)
{
  constexpr int M = 16384, K = 16384, BK = 128, BM = 64;
  constexpr int AT = BM * BK;            // 8192
  constexpr int BT = 256 * BK;           // 32768
  constexpr float SC = 256.f, SCI = 1.f / 256.f;

  __shared__ __align__(16) char LDS[2 * (AT + BT)];   // 80 KB

  const int tid = threadIdx.x;
  const int lane = tid & 63;
  const int wid = tid >> 6;
  const int wr = wid >> 2;   // M dim (2)
  const int wc = wid & 3;    // N dim (4)
  const int bm = blockIdx.x * BM;

  auto stage = [&](int half, int k0){
    char* ab = LDS + half * (AT + BT);
    { int e = tid * 16;
      int r = e >> 7, c = e & 127;
      int cc = c ^ ((r & 7) << 4);
      const unsigned char* g = A8 + (size_t)(bm + r) * K + k0 + cc;
      __builtin_amdgcn_global_load_lds((const __attribute__((address_space(1))) unsigned int*)g,
          (__attribute__((address_space(3))) unsigned int*)(ab + e), 16, 0, 0); }
    char* bb = ab + AT;
    #pragma unroll
    for (int i = 0; i < 4; i++){
      int e = (i * 512 + tid) * 16;
      int r = e >> 7, c = e & 127;
      int cc = c ^ ((r & 7) << 4);
      const unsigned char* g = B8 + (size_t)r * K + k0 + cc;
      __builtin_amdgcn_global_load_lds((const __attribute__((address_space(1))) unsigned int*)g,
          (__attribute__((address_space(3))) unsigned int*)(bb + e), 16, 0, 0);
    }
  };

  f32x16 acc[2];
  #pragma unroll
  for (int n = 0; n < 2; n++)
    #pragma unroll
    for (int i = 0; i < 16; i++) acc[n][i] = 0.f;

  stage(0, 0);
  for (int kt = 0; kt < K / BK; ++kt){
    __syncthreads();
    if (kt + 1 < K / BK) stage((kt + 1) & 1, (kt + 1) * BK);
    const char* ab = LDS + (kt & 1) * (AT + BT);
    const char* bb = ab + AT;
    #pragma unroll
    for (int ks = 0; ks < 2; ks++){
      const int c0 = ks * 64 + (lane >> 5) * 32;
      i32x8 af, bf_[2];
      { int r = wr * 32 + (lane & 31);
        int sw = (r & 7) << 4;
        int o = r * BK + c0;
        u32x4 lo = *(const u32x4*)(ab + (o ^ sw));
        u32x4 hi = *(const u32x4*)(ab + ((o + 16) ^ sw));
        af[0]=lo[0];af[1]=lo[1];af[2]=lo[2];af[3]=lo[3];
        af[4]=hi[0];af[5]=hi[1];af[6]=hi[2];af[7]=hi[3]; }
      #pragma unroll
      for (int n = 0; n < 2; n++){
        int r = wc * 64 + n * 32 + (lane & 31);
        int sw = (r & 7) << 4;
        int o = r * BK + c0;
        u32x4 lo = *(const u32x4*)(bb + (o ^ sw));
        u32x4 hi = *(const u32x4*)(bb + ((o + 16) ^ sw));
        bf_[n][0]=lo[0];bf_[n][1]=lo[1];bf_[n][2]=lo[2];bf_[n][3]=lo[3];
        bf_[n][4]=hi[0];bf_[n][5]=hi[1];bf_[n][6]=hi[2];bf_[n][7]=hi[3];
      }
      #pragma unroll
      for (int n = 0; n < 2; n++)
        acc[n] = __builtin_amdgcn_mfma_scale_f32_32x32x64_f8f6f4(
            af, bf_[n], acc[n], 0, 0, 0, 0x7F7F7F7F, 0, 0x7F7F7F7F);
    }
  }

  // ---- h3 -> LDS (bf16, swizzled), reusing stage space ----
  __syncthreads();
  u16* H3 = (u16*)LDS;            // [64][256] bf16 swizzled, 32 KB
  u16* B2 = (u16*)(LDS + 32768);  // [128][64] bf16 swizzled tile, 16 KB
  {
    int colg0 = wc * 64 + (lane & 31);
    int rb = wr * 32 + (lane >> 5) * 4;
    float gb0 = g1b[colg0], gb1 = g1b[colg0 + 32];
    #pragma unroll
    for (int i = 0; i < 16; i++){
      int row = rb + (i & 3) + 8 * (i >> 2);
      float dr = dis[bm + row] * SCI;
      float v0 = fmaxf(dr * acc[0][i] + gb0, 0.f);
      float v1 = fmaxf(dr * acc[1][i] + gb1, 0.f);
      *(u16*)((char*)H3 + (((row * 256 + colg0) * 2) ^ ((row & 7) << 4))) = f2bf(v0);
      *(u16*)((char*)H3 + (((row * 256 + colg0 + 32) * 2) ^ ((row & 7) << 4))) = f2bf(v1);
    }
  }

  // ---- phase 2: t2T = fp8(SC * dis * (H3 @ g2w))^T  (64x128 over K2=256) ----
  f32x4 acc2[2][2];
  #pragma unroll
  for (int m = 0; m < 2; m++)
    #pragma unroll
    for (int n = 0; n < 2; n++)
      acc2[m][n] = (f32x4){0.f, 0.f, 0.f, 0.f};
  const int kof = (lane >> 4) * 8;

  for (int kt2 = 0; kt2 < 4; ++kt2){
    s16x8 br[2];
    #pragma unroll
    for (int i = 0; i < 2; i++){
      int e = (i * 512 + tid) * 8; int r = e >> 6, c = e & 63;
      br[i] = *(const s16x8*)(g2t + (size_t)r * 256 + kt2 * 64 + c);
    }
    __syncthreads();  // prev MFMA reads of B2 done; (kt2=0: H3 writes done too)
    #pragma unroll
    for (int i = 0; i < 2; i++){
      int e = (i * 512 + tid) * 8; int r = e >> 6, c = e & 63;
      *(s16x8*)((char*)B2 + (((r * 64 + c) * 2) ^ ((r & 7) << 4))) = br[i];
    }
    __syncthreads();
    #pragma unroll
    for (int ks = 0; ks < 2; ++ks){
      s16x8 af[2], bf[2];
      #pragma unroll
      for (int m = 0; m < 2; m++){
        int r = wr * 32 + m * 16 + (lane & 15);
        af[m] = *(const s16x8*)((const char*)H3 + (((r * 256 + kt2 * 64 + ks * 32 + kof) * 2) ^ ((r & 7) << 4)));
      }
      #pragma unroll
      for (int n = 0; n < 2; n++){
        int r = wc * 32 + n * 16 + (lane & 15);
        bf[n] = *(const s16x8*)((const char*)B2 + (((r * 64 + ks * 32 + kof) * 2) ^ ((r & 7) << 4)));
      }
      #pragma unroll
      for (int m = 0; m < 2; m++)
        #pragma unroll
        for (int n = 0; n < 2; n++)
          acc2[m][n] = __builtin_amdgcn_mfma_f32_16x16x32_bf16(af[m], bf[n], acc2[m][n], 0, 0, 0);
    }
  }

  #pragma unroll
  for (int m = 0; m < 2; m++){
    #pragma unroll
    for (int n = 0; n < 2; n++){
      int col = wc * 32 + n * 16 + (lane & 15);
      int row0 = bm + wr * 32 + m * 16 + (lane >> 4) * 4;
      float v0 = acc2[m][n][0] * dis[row0 + 0] * SC;
      float v1 = acc2[m][n][1] * dis[row0 + 1] * SC;
      float v2 = acc2[m][n][2] * dis[row0 + 2] * SC;
      float v3 = acc2[m][n][3] * dis[row0 + 3] * SC;
      *(u32*)(t2T + (size_t)col * M + row0) = pk_fp8x4(v0, v1, v2, v3);
    }
  }
}

// ---------------- mx2 + cls fused: adj8 @ t2T -> h4(reg) -> LDS -> classifier -> out ----------------
__global__ __launch_bounds__(512, 4)
void mx2cls_kernel(const unsigned char* __restrict__ A8, const unsigned char* __restrict__ B8,
                   const float* __restrict__ dis, const float* __restrict__ g2b,
                   const float* __restrict__ cls_w, const float* __restrict__ cls_b,
                   float* __restrict__ out)
{
  constexpr int M = 16384, K = 16384, BK = 128, BM = 64;
  constexpr int AT = BM * BK;            // 8192
  constexpr int BT = 128 * BK;           // 16384
  constexpr float SCI = 1.f / 256.f;

  __shared__ __align__(16) char LDS[2 * (AT + BT)];   // 48 KB

  const int tid = threadIdx.x;
  const int lane = tid & 63;
  const int wid = tid >> 6;
  const int wr = wid >> 2;   // 2
  const int wc = wid & 3;    // 4
  const int bm = blockIdx.x * BM;

  auto stage = [&](int half, int k0){
    char* ab = LDS + half * (AT + BT);
    { int e = tid * 16;
      int r = e >> 7, c = e & 127;
      int cc = c ^ ((r & 7) << 4);
      const unsigned char* g = A8 + (size_t)(bm + r) * K + k0 + cc;
      __builtin_amdgcn_global_load_lds((const __attribute__((address_space(1))) unsigned int*)g,
          (__attribute__((address_space(3))) unsigned int*)(ab + e), 16, 0, 0); }
    char* bb = ab + AT;
    #pragma unroll
    for (int i = 0; i < 2; i++){
      int e = (i * 512 + tid) * 16;
      int r = e >> 7, c = e & 127;
      int cc = c ^ ((r & 7) << 4);
      const unsigned char* g = B8 + (size_t)r * K + k0 + cc;
      __builtin_amdgcn_global_load_lds((const __attribute__((address_space(1))) unsigned int*)g,
          (__attribute__((address_space(3))) unsigned int*)(bb + e), 16, 0, 0);
    }
  };

  f32x16 acc;
  #pragma unroll
  for (int i = 0; i < 16; i++) acc[i] = 0.f;

  stage(0, 0);
  for (int kt = 0; kt < K / BK; ++kt){
    __syncthreads();
    if (kt + 1 < K / BK) stage((kt + 1) & 1, (kt + 1) * BK);
    const char* ab = LDS + (kt & 1) * (AT + BT);
    const char* bb = ab + AT;
    #pragma unroll
    for (int ks = 0; ks < 2; ks++){
      const int c0 = ks * 64 + (lane >> 5) * 32;
      i32x8 af, bf_;
      { int r = wr * 32 + (lane & 31);
        int sw = (r & 7) << 4;
        int o = r * BK + c0;
        u32x4 lo = *(const u32x4*)(ab + (o ^ sw));
        u32x4 hi = *(const u32x4*)(ab + ((o + 16) ^ sw));
        af[0]=lo[0];af[1]=lo[1];af[2]=lo[2];af[3]=lo[3];
        af[4]=hi[0];af[5]=hi[1];af[6]=hi[2];af[7]=hi[3]; }
      { int r = wc * 32 + (lane & 31);
        int sw = (r & 7) << 4;
        int o = r * BK + c0;
        u32x4 lo = *(const u32x4*)(bb + (o ^ sw));
        u32x4 hi = *(const u32x4*)(bb + ((o + 16) ^ sw));
        bf_[0]=lo[0];bf_[1]=lo[1];bf_[2]=lo[2];bf_[3]=lo[3];
        bf_[4]=hi[0];bf_[5]=hi[1];bf_[6]=hi[2];bf_[7]=hi[3]; }
      acc = __builtin_amdgcn_mfma_scale_f32_32x32x64_f8f6f4(
          af, bf_, acc, 0, 0, 0, 0x7F7F7F7F, 0, 0x7F7F7F7F);
    }
  }

  // ---- h4 -> LDS f32 (stride 130), load classifier weights ----
  __syncthreads();
  float* H4  = (float*)LDS;                 // [64][130] f32 = 33280 B
  float* wsm = (float*)(LDS + 33280);       // [128][10]
  float* bsm = (float*)(LDS + 38400);       // [10]
  {
    int colg = wc * 32 + (lane & 31);
    int rb = wr * 32 + (lane >> 5) * 4;
    float gb = g2b[colg];
    #pragma unroll
    for (int i = 0; i < 16; i++){
      int row = rb + (i & 3) + 8 * (i >> 2);
      float vv = fmaxf(dis[bm + row] * SCI * acc[i] + gb, 0.f);
      H4[row * 130 + colg] = vv;
    }
  }
  for (int i = tid; i < 1280; i += 512) wsm[i] = cls_w[i];
  if (tid < 10) bsm[tid] = cls_b[tid];
  __syncthreads();

  // ---- classifier: 2 threads per row ----
  if (tid < 128){
    int row = tid >> 1, half = tid & 1;
    float a[10];
    #pragma unroll
    for (int c = 0; c < 10; c++) a[c] = 0.f;
    const float* hp = H4 + row * 130 + half * 64;
    const float* wp0 = wsm + half * 64 * 10;
    for (int k = 0; k < 64; ++k){
      float h = hp[k];
      #pragma unroll
      for (int c = 0; c < 10; c++) a[c] = fmaf(h, wp0[k * 10 + c], a[c]);
    }
    #pragma unroll
    for (int c = 0; c < 10; c++) a[c] += __shfl_xor(a[c], 1);
    if (half == 0){
      #pragma unroll
      for (int c = 0; c < 10; c++){
        float sg = 1.f / (1.f + expf(-(a[c] + bsm[c])));
        sg = fminf(fmaxf(sg, 1e-10f), 1.f - 1e-10f);
        out[(size_t)(bm + row) * 10 + c] = sg;
      }
    }
  }
}

// ---------------- launcher ----------------

extern "C" void kernel_launch(void* const* d_in, const int* in_sizes, int n_in,
                              void* d_out, int out_size, void* d_ws, size_t ws_size,
                              hipStream_t stream)
{
  (void)in_sizes; (void)n_in; (void)out_size; (void)ws_size;
  const float* feature = (const float*)d_in[0];
  const float* adj     = (const float*)d_in[1];
  const float* enc_w1  = (const float*)d_in[2];
  const float* enc_b1  = (const float*)d_in[3];
  const float* bn1_g   = (const float*)d_in[4];
  const float* bn1_b   = (const float*)d_in[5];
  const float* bn1_m   = (const float*)d_in[6];
  const float* bn1_v   = (const float*)d_in[7];
  const float* enc_w2  = (const float*)d_in[8];
  const float* enc_b2  = (const float*)d_in[9];
  const float* bn2_g   = (const float*)d_in[10];
  const float* bn2_b   = (const float*)d_in[11];
  const float* bn2_m   = (const float*)d_in[12];
  const float* bn2_v   = (const float*)d_in[13];
  const float* gcn1_w  = (const float*)d_in[14];
  const float* gcn1_b  = (const float*)d_in[15];
  const float* gcn2_w  = (const float*)d_in[16];
  const float* gcn2_b  = (const float*)d_in[17];
  const float* cls_w   = (const float*)d_in[18];
  const float* cls_b   = (const float*)d_in[19];
  float* out = (float*)d_out;

  const int NN = 16384, F = 1024, H1 = 512, E = 256, H = 256, G = 128;

  char* ws = (char*)d_ws;
  size_t off = 0;
  auto alloc = [&](size_t bytes) -> char* {
    char* p = ws + off; off += (bytes + 255) & ~(size_t)255; return p;
  };
  float* dis = (float*)alloc((size_t)NN * 4);
  float* s1  = (float*)alloc((size_t)H1 * 4);
  float* bb1 = (float*)alloc((size_t)H1 * 4);
  float* s2  = (float*)alloc((size_t)E * 4);
  float* bb2 = (float*)alloc((size_t)E * 4);
  u16* w1t = (u16*)alloc((size_t)H1 * F * 2);
  u16* w2t = (u16*)alloc((size_t)E * H1 * 2);
  u16* g1t = (u16*)alloc((size_t)H * E * 2);
  u16* g2t = (u16*)alloc((size_t)G * H * 2);
  u16* h1  = (u16*)alloc((size_t)NN * H1 * 2);
  unsigned char* tT  = (unsigned char*)alloc((size_t)E * NN);
  unsigned char* t2T = (unsigned char*)alloc((size_t)G * NN);
  unsigned char* adj8 = (unsigned char*)alloc((size_t)NN * NN);

  // 1) w1 transpose-convert + bn1 fold
  prep0_kernel<<<514, 256, 0, stream>>>(enc_w1, w1t, bn1_g, bn1_b, bn1_m, bn1_v, enc_b1, s1, bb1);

  // 2) fused: enc1 GEMM + degree/fp8 convert + w2t/g1t/g2t/bn2 preps
  enc1_deg_kernel<<<256 + NN + 225, 256, 0, stream>>>(
      feature, w1t, h1, s1, bb1, adj, adj8, dis,
      enc_w2, w2t, gcn1_w, g1t, gcn2_w, g2t,
      bn2_g, bn2_b, bn2_m, bn2_v, enc_b2, s2, bb2);

  // 3) fused enc2 + gcn1 prescale -> tT (fp8, transposed)
  h2tT_kernel<<<NN / 64, 512, 0, stream>>>(h1, w2t, s2, bb2, g1t, dis, tT);

  // 4) fused GCN1 aggregation + gcn2 feature GEMM -> t2T (fp8, transposed)
  mx1t2_kernel<<<NN / 64, 512, 0, stream>>>(adj8, tT, dis, gcn1_b, g2t, t2T);

  // 5) fused GCN2 aggregation + classifier -> out
  mx2cls_kernel<<<NN / 64, 512, 0, stream>>>(adj8, t2T, dis, gcn2_b, cls_w, cls_b, out);
}